// Round 1
// baseline (662.728 us; speedup 1.0000x reference)
//
#include <hip/hip_runtime.h>
#include <hip/hip_bf16.h>

// SizeInvBlock: upsample3x(nearest) -> per-sample dilated 3x3 conv -> maxpool3 -> BN(train) -> relu
// Factorization: conv on upsampled image only samples original 32x32 pixels:
//   out[o,y,x] = bias[o] + sum_{ki,kj} T[kikj][o, r_ki(y), c_kj(x)]
//   T[kikj][o,i,j] = sum_c W[o,c,ki,kj] * X[c,i,j]   (one GEMM, 9x fewer FLOPs than direct conv)
//
// ws layout (bytes), total ~44.2 MB:
//   [0,      1024)  stats: sum[128], sumsq[128] (f32, atomically accumulated)
//   [4096,  151552) Abf16 [1152][64]   (m = (ki*3+kj)*128 + o, k = cin)
//   [151552,8540160) Xbf16 [64][64][1024]
//   [8540160, 46288896) T bf16 [1152][16384]  (chunk of 16 samples, n = bl*1024 + i*32 + j)

typedef __attribute__((ext_vector_type(8))) short bf16x8;
typedef __attribute__((ext_vector_type(4))) float f32x4;
typedef __attribute__((ext_vector_type(8))) unsigned short us8;
typedef __attribute__((ext_vector_type(4))) unsigned short us4;

#define CHB 16          // samples per chunk
#define CHN (CHB*1024)  // T n-dimension per chunk

__device__ __forceinline__ unsigned short f2bf(float f) {
    unsigned u = __float_as_uint(f);
    u += 0x7fffu + ((u >> 16) & 1u);
    return (unsigned short)(u >> 16);
}
__device__ __forceinline__ float bf2f(unsigned short s) {
    return __uint_as_float(((unsigned)s) << 16);
}

// ---- K0a: X fp32 -> bf16 -------------------------------------------------
__global__ __launch_bounds__(256) void k0_x(const float4* __restrict__ x, us4* __restrict__ xb) {
    int i = blockIdx.x * 256 + threadIdx.x;   // 0..1048575
    float4 v = x[i];
    us4 r;
    r[0] = f2bf(v.x); r[1] = f2bf(v.y); r[2] = f2bf(v.z); r[3] = f2bf(v.w);
    xb[i] = r;
}

// ---- K0b: W fp32 [o][c][ki][kj] -> A bf16 [(kikj)*128+o][c] --------------
__global__ __launch_bounds__(256) void k0_w(const float* __restrict__ w, unsigned short* __restrict__ A) {
    int gid = blockIdx.x * 256 + threadIdx.x;  // < 73728
    int m = gid >> 6, c = gid & 63;
    int kk = m >> 7, o = m & 127;
    A[gid] = f2bf(w[(o * 64 + c) * 9 + kk]);
}

// ---- K1: GEMM A[1152x64] @ Xchunk[64 x CHN] -> T bf16 --------------------
// block: 256 thr (4 waves), tile 64M x 128N, K=64 (2 MFMA k-steps of 32).
__global__ __launch_bounds__(256) void k1_gemm(const unsigned short* __restrict__ Xc,
                                               const unsigned short* __restrict__ A,
                                               unsigned short* __restrict__ T) {
    __shared__ unsigned short lA[64 * 72];   // [m][k], stride 72 (2-way bank pattern)
    __shared__ unsigned short lB[128 * 72];  // [n][k] (B transposed)
    const int tid = threadIdx.x;
    const int nt = blockIdx.x;      // 0..CHN/128-1
    const int mt = blockIdx.y;      // 0..17

    // stage A: 64x64 bf16, same layout as global (k-contig)
    #pragma unroll
    for (int i = 0; i < 2; ++i) {
        int gid = i * 256 + tid;            // 0..511
        int row = gid >> 3, ch = gid & 7;
        us8 v = *reinterpret_cast<const us8*>(A + (size_t)(mt * 64 + row) * 64 + ch * 8);
        *reinterpret_cast<us8*>(&lA[row * 72 + ch * 8]) = v;
    }
    // stage B: 64k x 128n, transpose into [n][k]
    const int bl = nt >> 3;
    const int ij0 = (nt & 7) * 128;
    #pragma unroll
    for (int i = 0; i < 4; ++i) {
        int gid = i * 256 + tid;            // 0..1023
        int c = gid >> 4, ch = gid & 15;
        int n0 = ch * 8;
        us8 v = *reinterpret_cast<const us8*>(Xc + (size_t)bl * 65536 + c * 1024 + ij0 + n0);
        #pragma unroll
        for (int j = 0; j < 8; ++j) lB[(n0 + j) * 72 + c] = v[j];
    }
    __syncthreads();

    const int wave = tid >> 6, lane = tid & 63;
    const int quad = lane >> 4, l15 = lane & 15;
    f32x4 acc[8] = {};
    #pragma unroll
    for (int ks = 0; ks < 2; ++ks) {
        int koff = ks * 32 + quad * 8;
        bf16x8 a = *reinterpret_cast<const bf16x8*>(&lA[(wave * 16 + l15) * 72 + koff]);
        #pragma unroll
        for (int ns = 0; ns < 8; ++ns) {
            bf16x8 b = *reinterpret_cast<const bf16x8*>(&lB[(ns * 16 + l15) * 72 + koff]);
            acc[ns] = __builtin_amdgcn_mfma_f32_16x16x32_bf16(a, b, acc[ns], 0, 0, 0);
        }
    }
    // C/D: col = lane&15 (n), row = quad*4 + reg (m)
    const int mbase = mt * 64 + wave * 16 + quad * 4;
    const int nbase = nt * 128 + l15;
    #pragma unroll
    for (int ns = 0; ns < 8; ++ns)
        #pragma unroll
        for (int r = 0; r < 4; ++r)
            T[(size_t)(mbase + r) * CHN + nbase + ns * 16] = f2bf(acc[ns][r]);
}

// ---- K2: gather 81 taps, sum over (ki,kj), maxpool3, bias, BN stats ------
// grid: (o-chunks=16, p=32, bl=CHB); thread: q = tid&31, oi = tid>>5
__global__ __launch_bounds__(256) void k2_gather(const unsigned short* __restrict__ T,
                                                 const float* __restrict__ bias,
                                                 const int* __restrict__ hh,
                                                 const int* __restrict__ ww,
                                                 float* __restrict__ out,
                                                 float* __restrict__ stats,
                                                 int b0) {
    const int tid = threadIdx.x;
    const int q = tid & 31, oi = tid >> 5;
    const int oc = blockIdx.x, p = blockIdx.y, bl = blockIdx.z;
    const int o = oc * 8 + oi;
    const int b = b0 + bl;
    int dh = 96 / hh[b]; if (dh < 1) dh = 1;
    int dw = 96 / ww[b]; if (dw < 1) dw = 1;

    int rr[3][3], cc[3][3];
    #pragma unroll
    for (int ki = 0; ki < 3; ++ki)
        #pragma unroll
        for (int y3 = 0; y3 < 3; ++y3) {
            int v = 3 * p + y3 + (ki - 1) * dh;
            rr[ki][y3] = (v >= 0 && v < 96) ? (v / 3) : -1;   // block-uniform
        }
    #pragma unroll
    for (int kj = 0; kj < 3; ++kj)
        #pragma unroll
        for (int x3 = 0; x3 < 3; ++x3) {
            int v = 3 * q + x3 + (kj - 1) * dw;
            cc[kj][x3] = (v >= 0 && v < 96) ? (v / 3) : -1;
        }

    const unsigned short* Tb = T + (size_t)o * CHN + bl * 1024;
    float best = -1e30f;
    #pragma unroll
    for (int y3 = 0; y3 < 3; ++y3) {
        #pragma unroll
        for (int x3 = 0; x3 < 3; ++x3) {
            float s = 0.f;
            #pragma unroll
            for (int ki = 0; ki < 3; ++ki) {
                int r = rr[ki][y3];
                if (r < 0) continue;                 // uniform branch
                #pragma unroll
                for (int kj = 0; kj < 3; ++kj) {
                    int c = cc[kj][x3];
                    if (c >= 0)
                        s += bf2f(Tb[(size_t)(ki * 3 + kj) * 128 * CHN + r * 32 + c]);
                }
            }
            best = fmaxf(best, s);
        }
    }
    float val = best + bias[o];
    out[(((size_t)b * 128 + o) * 32 + p) * 32 + q] = val;

    float s1 = val, s2 = val * val;
    #pragma unroll
    for (int m = 16; m >= 1; m >>= 1) {
        s1 += __shfl_xor(s1, m, 32);
        s2 += __shfl_xor(s2, m, 32);
    }
    if (q == 0) {
        atomicAdd(&stats[o], s1);
        atomicAdd(&stats[128 + o], s2);
    }
}

// ---- K3: BN finalize + affine + relu, in-place on d_out ------------------
__global__ __launch_bounds__(256) void k3_bn(float4* __restrict__ out,
                                             const float* __restrict__ stats,
                                             const float* __restrict__ gamma,
                                             const float* __restrict__ beta) {
    int i4 = blockIdx.x * 256 + threadIdx.x;   // 0..2097151
    int o = (i4 >> 8) & 127;
    const float invN = 1.0f / 65536.0f;
    float mean = stats[o] * invN;
    float var = stats[128 + o] * invN - mean * mean;
    float inv = rsqrtf(var + 1e-5f);
    float sc = gamma[o] * inv;
    float sh = beta[o] - mean * sc;
    float4 v = out[i4];
    v.x = fmaxf(fmaf(v.x, sc, sh), 0.f);
    v.y = fmaxf(fmaf(v.y, sc, sh), 0.f);
    v.z = fmaxf(fmaf(v.z, sc, sh), 0.f);
    v.w = fmaxf(fmaf(v.w, sc, sh), 0.f);
    out[i4] = v;
}

extern "C" void kernel_launch(void* const* d_in, const int* in_sizes, int n_in,
                              void* d_out, int out_size, void* d_ws, size_t ws_size,
                              hipStream_t stream) {
    const float* x     = (const float*)d_in[0];
    const int*   h     = (const int*)d_in[1];
    const int*   w     = (const int*)d_in[2];
    const float* wt    = (const float*)d_in[3];
    const float* bias  = (const float*)d_in[4];
    const float* gamma = (const float*)d_in[5];
    const float* beta  = (const float*)d_in[6];
    float* out = (float*)d_out;
    char* ws = (char*)d_ws;

    float*          stats = (float*)(ws + 0);
    unsigned short* A     = (unsigned short*)(ws + 4096);
    unsigned short* Xb    = (unsigned short*)(ws + 151552);
    unsigned short* T     = (unsigned short*)(ws + 8540160);

    hipMemsetAsync(stats, 0, 1024, stream);
    k0_x<<<4096, 256, 0, stream>>>((const float4*)x, (us4*)Xb);
    k0_w<<<288, 256, 0, stream>>>(wt, A);
    for (int ch = 0; ch < 64 / CHB; ++ch) {
        k1_gemm<<<dim3(CHN / 128, 18), 256, 0, stream>>>(Xb + (size_t)ch * CHB * 65536, A, T);
        k2_gather<<<dim3(16, 32, CHB), 256, 0, stream>>>(T, bias, h, w, out, stats, ch * CHB);
    }
    k3_bn<<<8192, 256, 0, stream>>>((float4*)out, stats, gamma, beta);
}

// Round 3
// 334.977 us; speedup vs baseline: 1.9784x; 1.9784x over previous
//
#include <hip/hip_runtime.h>
#include <hip/hip_bf16.h>

// SizeInvBlock: upsample3x(nearest) -> per-sample dilated 3x3 conv -> maxpool3 -> BN(train) -> relu
// Factorization: conv on upsampled image only samples original 32x32 pixels:
//   out[o,y,x] = bias[o] + sum_{ki,kj} T[kikj][o, r_ki(y), c_kj(x)]
//   T[kikj][o,i,j] = sum_c W[o,c,ki,kj] * X[c,i,j]   (one GEMM, 9x fewer FLOPs than direct conv)
// R3: fix R2 pad-zero typo (c+28 -> c+32): right pad is cols 36..39, not 32..35
// (32..35 are data; zeroing them raced with staging and left 36..39 garbage).
//
// ws layout (bytes), total ~44.2 MB:
//   [0,      1024)  stats: sum[128], sumsq[128] (f32, atomically accumulated)
//   [4096,  151552) Abf16 [1152][64]   (m = (ki*3+kj)*128 + o, k = cin)
//   [151552,8540160) Xbf16 [64][64][1024]
//   [8540160, 46288896) T bf16 [1152][16384]  (chunk of 16 samples, n = bl*1024 + i*32 + j)

typedef __attribute__((ext_vector_type(8))) short bf16x8;
typedef __attribute__((ext_vector_type(4))) float f32x4;
typedef __attribute__((ext_vector_type(8))) unsigned short us8;
typedef __attribute__((ext_vector_type(4))) unsigned short us4;

#define CHB 16          // samples per chunk
#define CHN (CHB*1024)  // T n-dimension per chunk

__device__ __forceinline__ unsigned short f2bf(float f) {
    unsigned u = __float_as_uint(f);
    u += 0x7fffu + ((u >> 16) & 1u);
    return (unsigned short)(u >> 16);
}
__device__ __forceinline__ float bf2f(unsigned short s) {
    return __uint_as_float(((unsigned)s) << 16);
}
__device__ __forceinline__ int floordiv3(int t) {
    return (t >= 0) ? (t / 3) : -((2 - t) / 3);
}

// ---- K0a: X fp32 -> bf16 -------------------------------------------------
__global__ __launch_bounds__(256) void k0_x(const float4* __restrict__ x, us4* __restrict__ xb) {
    int i = blockIdx.x * 256 + threadIdx.x;   // 0..1048575
    float4 v = x[i];
    us4 r;
    r[0] = f2bf(v.x); r[1] = f2bf(v.y); r[2] = f2bf(v.z); r[3] = f2bf(v.w);
    xb[i] = r;
}

// ---- K0b: W fp32 [o][c][ki][kj] -> A bf16 [(kikj)*128+o][c] --------------
__global__ __launch_bounds__(256) void k0_w(const float* __restrict__ w, unsigned short* __restrict__ A) {
    int gid = blockIdx.x * 256 + threadIdx.x;  // < 73728
    int m = gid >> 6, c = gid & 63;
    int kk = m >> 7, o = m & 127;
    A[gid] = f2bf(w[(o * 64 + c) * 9 + kk]);
}

// ---- K1: GEMM A[1152x64] @ Xchunk[64 x CHN] -> T bf16 --------------------
// block: 256 thr (4 waves), tile 64M x 128N, K=64 (2 MFMA k-steps of 32).
__global__ __launch_bounds__(256) void k1_gemm(const unsigned short* __restrict__ Xc,
                                               const unsigned short* __restrict__ A,
                                               unsigned short* __restrict__ T) {
    __shared__ unsigned short lA[64 * 72];   // [m][k], stride 72 (2-way bank pattern)
    __shared__ unsigned short lB[128 * 72];  // [n][k] (B transposed)
    const int tid = threadIdx.x;
    const int nt = blockIdx.x;      // 0..CHN/128-1
    const int mt = blockIdx.y;      // 0..17

    // stage A: 64x64 bf16, same layout as global (k-contig)
    #pragma unroll
    for (int i = 0; i < 2; ++i) {
        int gid = i * 256 + tid;            // 0..511
        int row = gid >> 3, ch = gid & 7;
        us8 v = *reinterpret_cast<const us8*>(A + (size_t)(mt * 64 + row) * 64 + ch * 8);
        *reinterpret_cast<us8*>(&lA[row * 72 + ch * 8]) = v;
    }
    // stage B: 64k x 128n, transpose into [n][k]
    const int bl = nt >> 3;
    const int ij0 = (nt & 7) * 128;
    #pragma unroll
    for (int i = 0; i < 4; ++i) {
        int gid = i * 256 + tid;            // 0..1023
        int c = gid >> 4, ch = gid & 15;
        int n0 = ch * 8;
        us8 v = *reinterpret_cast<const us8*>(Xc + (size_t)bl * 65536 + c * 1024 + ij0 + n0);
        #pragma unroll
        for (int j = 0; j < 8; ++j) lB[(n0 + j) * 72 + c] = v[j];
    }
    __syncthreads();

    const int wave = tid >> 6, lane = tid & 63;
    const int quad = lane >> 4, l15 = lane & 15;
    f32x4 acc[8] = {};
    #pragma unroll
    for (int ks = 0; ks < 2; ++ks) {
        int koff = ks * 32 + quad * 8;
        bf16x8 a = *reinterpret_cast<const bf16x8*>(&lA[(wave * 16 + l15) * 72 + koff]);
        #pragma unroll
        for (int ns = 0; ns < 8; ++ns) {
            bf16x8 b = *reinterpret_cast<const bf16x8*>(&lB[(ns * 16 + l15) * 72 + koff]);
            acc[ns] = __builtin_amdgcn_mfma_f32_16x16x32_bf16(a, b, acc[ns], 0, 0, 0);
        }
    }
    // C/D: col = lane&15 (n), row = quad*4 + reg (m)
    const int mbase = mt * 64 + wave * 16 + quad * 4;
    const int nbase = nt * 128 + l15;
    #pragma unroll
    for (int ns = 0; ns < 8; ++ns)
        #pragma unroll
        for (int r = 0; r < 4; ++r)
            T[(size_t)(mbase + r) * CHN + nbase + ns * 16] = f2bf(acc[ns][r]);
}

// ---- K2: LDS-staged gather: 81 taps, sum(ki,kj), maxpool3, bias, BN stats
// grid: (o=128, bl=CHB), block 256. Each block owns one (b,o) pair.
// LDS: 9 planes, each 33 rows x 40 f32 (rows 0..31 data with 4-col zero pads
// both sides; row 32 all-zero for row-OOB). col index = q + floor(t/3)+4.
#define PLS (33 * 40)   // plane stride in floats = 1320
__global__ __launch_bounds__(256) void k2_gather(const unsigned short* __restrict__ T,
                                                 const float* __restrict__ bias,
                                                 const int* __restrict__ hh,
                                                 const int* __restrict__ ww,
                                                 float* __restrict__ out,
                                                 float* __restrict__ stats,
                                                 int b0) {
    __shared__ float lt[9 * PLS];   // 47520 B
    const int tid = threadIdx.x;
    const int o = blockIdx.x;       // 0..127
    const int bl = blockIdx.y;      // 0..CHB-1
    const int b = b0 + bl;

    // zero pad columns (rows 0..31, cols {0..3, 36..39}) of each plane
    #pragma unroll 3
    for (int i = tid; i < 9 * 32 * 8; i += 256) {
        int pr = i >> 3, c = i & 7;
        int kk = pr >> 5, r = pr & 31;
        lt[kk * PLS + r * 40 + (c < 4 ? c : c + 32)] = 0.f;   // pads {0..3, 36..39}
    }
    // zero row 32 of each plane
    for (int i = tid; i < 9 * 40; i += 256) {
        int kk = i / 40, c = i - kk * 40;
        lt[kk * PLS + 32 * 40 + c] = 0.f;
    }
    // stage 9 planes (each 1024 bf16 contiguous) -> f32 into padded rows
    const unsigned short* Tb = T + (size_t)o * CHN + (size_t)bl * 1024;
    for (int i = tid; i < 9 * 128; i += 256) {
        int kk = i >> 7, c8 = i & 127;          // c8: which us8 within plane
        us8 v = *reinterpret_cast<const us8*>(Tb + (size_t)kk * 128 * CHN + c8 * 8);
        int r = c8 >> 2;                         // 4 us8 per 32-col row
        int cb = (c8 & 3) * 8;
        float* dst = &lt[kk * PLS + r * 40 + 4 + cb];
        f32x4 lo, hi;
        lo[0] = bf2f(v[0]); lo[1] = bf2f(v[1]); lo[2] = bf2f(v[2]); lo[3] = bf2f(v[3]);
        hi[0] = bf2f(v[4]); hi[1] = bf2f(v[5]); hi[2] = bf2f(v[6]); hi[3] = bf2f(v[7]);
        *reinterpret_cast<f32x4*>(dst) = lo;
        *reinterpret_cast<f32x4*>(dst + 4) = hi;
    }
    __syncthreads();

    int dh = 96 / hh[b]; if (dh < 1) dh = 1;
    int dw = 96 / ww[b]; if (dw < 1) dw = 1;
    const int q = tid & 31, prow = tid >> 5;
    const int qb = (q + 4) * 4;                  // col byte base incl. +4 pad bias

    // column byte offsets per (kj,x3): f*4, f in [-4,4]
    int cOffB[9];
    #pragma unroll
    for (int kj = 0; kj < 3; ++kj)
        #pragma unroll
        for (int x3 = 0; x3 < 3; ++x3)
            cOffB[kj * 3 + x3] = floordiv3(x3 + (kj - 1) * dw) * 4;
    // row deltas per (ki,y3)
    int g[9];
    #pragma unroll
    for (int ki = 0; ki < 3; ++ki)
        #pragma unroll
        for (int y3 = 0; y3 < 3; ++y3)
            g[ki * 3 + y3] = floordiv3(y3 + (ki - 1) * dh);

    const float bias_o = bias[o];
    const char* ltc = (const char*)lt;
    float s1 = 0.f, s2 = 0.f;
    #pragma unroll
    for (int it = 0; it < 4; ++it) {
        const int p = prow + it * 8;
        int rbB[9];                              // row byte base per (ki,y3)
        #pragma unroll
        for (int j = 0; j < 9; ++j) {
            int r = p + g[j];
            int rcl = ((unsigned)r < 32u) ? r : 32;   // 32 = zero row
            rbB[j] = rcl * 160 + qb;
        }
        float best = -3.4e38f;
        #pragma unroll
        for (int y3 = 0; y3 < 3; ++y3) {
            #pragma unroll
            for (int x3 = 0; x3 < 3; ++x3) {
                float s = 0.f;
                #pragma unroll
                for (int ki = 0; ki < 3; ++ki) {
                    #pragma unroll
                    for (int kj = 0; kj < 3; ++kj) {
                        int kk = ki * 3 + kj;
                        s += *reinterpret_cast<const float*>(
                            ltc + kk * (PLS * 4) + rbB[ki * 3 + y3] + cOffB[kj * 3 + x3]);
                    }
                }
                best = fmaxf(best, s);
            }
        }
        float val = best + bias_o;
        out[(((size_t)b * 128 + o) * 32 + p) * 32 + q] = val;
        s1 += val;
        s2 += val * val;
    }
    // full-wave (64-lane) reduction, one atomic pair per wave
    #pragma unroll
    for (int m = 32; m >= 1; m >>= 1) {
        s1 += __shfl_xor(s1, m, 64);
        s2 += __shfl_xor(s2, m, 64);
    }
    if ((tid & 63) == 0) {
        atomicAdd(&stats[o], s1);
        atomicAdd(&stats[128 + o], s2);
    }
}

// ---- K3: BN finalize + affine + relu, in-place on d_out ------------------
__global__ __launch_bounds__(256) void k3_bn(float4* __restrict__ out,
                                             const float* __restrict__ stats,
                                             const float* __restrict__ gamma,
                                             const float* __restrict__ beta) {
    int i4 = blockIdx.x * 256 + threadIdx.x;   // 0..2097151
    int o = (i4 >> 8) & 127;
    const float invN = 1.0f / 65536.0f;
    float mean = stats[o] * invN;
    float var = stats[128 + o] * invN - mean * mean;
    float inv = rsqrtf(var + 1e-5f);
    float sc = gamma[o] * inv;
    float sh = beta[o] - mean * sc;
    float4 v = out[i4];
    v.x = fmaxf(fmaf(v.x, sc, sh), 0.f);
    v.y = fmaxf(fmaf(v.y, sc, sh), 0.f);
    v.z = fmaxf(fmaf(v.z, sc, sh), 0.f);
    v.w = fmaxf(fmaf(v.w, sc, sh), 0.f);
    out[i4] = v;
}

extern "C" void kernel_launch(void* const* d_in, const int* in_sizes, int n_in,
                              void* d_out, int out_size, void* d_ws, size_t ws_size,
                              hipStream_t stream) {
    const float* x     = (const float*)d_in[0];
    const int*   h     = (const int*)d_in[1];
    const int*   w     = (const int*)d_in[2];
    const float* wt    = (const float*)d_in[3];
    const float* bias  = (const float*)d_in[4];
    const float* gamma = (const float*)d_in[5];
    const float* beta  = (const float*)d_in[6];
    float* out = (float*)d_out;
    char* ws = (char*)d_ws;

    float*          stats = (float*)(ws + 0);
    unsigned short* A     = (unsigned short*)(ws + 4096);
    unsigned short* Xb    = (unsigned short*)(ws + 151552);
    unsigned short* T     = (unsigned short*)(ws + 8540160);

    hipMemsetAsync(stats, 0, 1024, stream);
    k0_x<<<4096, 256, 0, stream>>>((const float4*)x, (us4*)Xb);
    k0_w<<<288, 256, 0, stream>>>(wt, A);
    for (int ch = 0; ch < 64 / CHB; ++ch) {
        k1_gemm<<<dim3(CHN / 128, 18), 256, 0, stream>>>(Xb + (size_t)ch * CHB * 65536, A, T);
        k2_gather<<<dim3(128, CHB), 256, 0, stream>>>(T, bias, h, w, out, stats, ch * CHB);
    }
    k3_bn<<<8192, 256, 0, stream>>>((float4*)out, stats, gamma, beta);
}

// Round 4
// 235.099 us; speedup vs baseline: 2.8189x; 1.4248x over previous
//
#include <hip/hip_runtime.h>
#include <hip/hip_bf16.h>

// SizeInvBlock: upsample3x(nearest) -> per-sample dilated 3x3 conv -> maxpool3 -> BN(train) -> relu
// Factorization: conv on upsampled image only samples original 32x32 pixels:
//   out[o,y,x] = bias[o] + sum_{ki,kj} T[kikj][o, r_ki(y), c_kj(x)]
//   T[kikj][o,i,j] = sum_c W[o,c,ki,kj] * X[c,i,j]   (one GEMM, 9x fewer FLOPs than direct conv)
// R4: (1) k0_x now transposes X -> XbT[b][n][c] bf16 so k1 staging has no LDS transpose
//     (2) k1: single launch, 128x128 tile, LDS in 16B units interleaved by k-group
//         (unit = kg*129 + row): contiguous ds_read_b128 frags, bank-balanced staging writes
//     (3) k2: 36 unique taps (floor((t+y3)/3) takes <=2 values over y3=0..2) ->
//         2 rows x 2 cols per plane via ds_read2_b32; 9 pool candidates = uniform selects
//
// ws layout (bytes), ~159.5 MB total (ws >= 256 MB per fill evidence):
//   [0,      1024)    stats: sum[128], sumsq[128] (f32, atomic)
//   [4096,   151552)  A bf16 [1152][64]   (m = (ki*3+kj)*128 + o, k = cin)
//   [151552, 8540160) XbT bf16 [64 b][1024 n][64 c]
//   [8540160,159535104) T bf16 [1152][65536]  (n = b*1024 + i*32 + j)

typedef __attribute__((ext_vector_type(8))) short bf16x8;
typedef __attribute__((ext_vector_type(4))) float f32x4;
typedef __attribute__((ext_vector_type(8))) unsigned short us8;

#define BN 65536   // T n-dimension (all 64 samples)

__device__ __forceinline__ unsigned short f2bf(float f) {
    unsigned u = __float_as_uint(f);
    u += 0x7fffu + ((u >> 16) & 1u);
    return (unsigned short)(u >> 16);
}
__device__ __forceinline__ float bf2f(unsigned short s) {
    return __uint_as_float(((unsigned)s) << 16);
}
__device__ __forceinline__ int floordiv3(int t) {
    return (t >= 0) ? (t / 3) : -((2 - t) / 3);
}

// ---- K0a: X fp32 [b][c][1024] -> XbT bf16 [b][n][c] ----------------------
// grid (16 ntile, 64 b), 256 thr: n_in = tid&63 (coalesced loads), cg = tid>>6
__global__ __launch_bounds__(256) void k0_x(const float* __restrict__ x,
                                            unsigned short* __restrict__ xbt) {
    const int tid = threadIdx.x;
    const int n = blockIdx.x * 64 + (tid & 63);
    const int cg = tid >> 6;
    const int b = blockIdx.y;
    #pragma unroll
    for (int j2 = 0; j2 < 2; ++j2) {
        int c8 = cg * 2 + j2;                     // 0..7
        us8 r;
        #pragma unroll
        for (int j = 0; j < 8; ++j)
            r[j] = f2bf(x[(((b << 6) + c8 * 8 + j) << 10) + n]);
        *reinterpret_cast<us8*>(xbt + ((size_t)(b << 10) + n) * 64 + c8 * 8) = r;
    }
}

// ---- K0b: W fp32 [o][c][ki][kj] -> A bf16 [(kikj)*128+o][c] --------------
__global__ __launch_bounds__(256) void k0_w(const float* __restrict__ w, unsigned short* __restrict__ A) {
    int gid = blockIdx.x * 256 + threadIdx.x;  // < 73728
    int m = gid >> 6, c = gid & 63;
    int kk = m >> 7, o = m & 127;
    A[gid] = f2bf(w[(o * 64 + c) * 9 + kk]);
}

// ---- K1: GEMM A[1152x64] @ XbT^T[64 x 65536] -> T bf16 -------------------
// grid (512 nt, 9 mt), 256 thr (4 waves, 2x2 wave grid), tile 128m x 128n, K=64.
// LDS: 16B units, unit index = kg*129 + row (kg = k/8 in 0..7).
__global__ __launch_bounds__(256) void k1_gemm(const unsigned short* __restrict__ XbT,
                                               const unsigned short* __restrict__ A,
                                               unsigned short* __restrict__ T) {
    __shared__ us8 lA[8 * 129];   // 16.5 KB
    __shared__ us8 lB[8 * 129];   // 16.5 KB
    const int tid = threadIdx.x;
    const int nt = blockIdx.x;    // 0..511
    const int mt = blockIdx.y;    // 0..8

    // stage A tile: rows mt*128..+127, 8 us8 per row
    #pragma unroll
    for (int i = 0; i < 4; ++i) {
        int gid = i * 256 + tid;          // 0..1023
        int row = gid >> 3, ch = gid & 7; // ch fastest -> coalesced 16B/lane
        lA[ch * 129 + row] = *reinterpret_cast<const us8*>(
            A + (size_t)(mt * 128 + row) * 64 + ch * 8);
    }
    // stage B tile: XbT rows nt*128..+127 (already [n][k])
    #pragma unroll
    for (int i = 0; i < 4; ++i) {
        int gid = i * 256 + tid;
        int row = gid >> 3, ch = gid & 7;
        lB[ch * 129 + row] = *reinterpret_cast<const us8*>(
            XbT + ((size_t)nt * 128 + row) * 64 + ch * 8);
    }
    __syncthreads();

    const int wave = tid >> 6, lane = tid & 63;
    const int quad = lane >> 4, l15 = lane & 15;
    const int wm = wave & 1, wn = wave >> 1;
    const bf16x8* pA = reinterpret_cast<const bf16x8*>(lA);
    const bf16x8* pB = reinterpret_cast<const bf16x8*>(lB);

    f32x4 acc[4][4] = {};
    #pragma unroll
    for (int ks = 0; ks < 2; ++ks) {
        const int kg = ks * 4 + quad;
        bf16x8 aF[4], bF[4];
        #pragma unroll
        for (int mi = 0; mi < 4; ++mi)
            aF[mi] = pA[kg * 129 + wm * 64 + mi * 16 + l15];
        #pragma unroll
        for (int ni = 0; ni < 4; ++ni)
            bF[ni] = pB[kg * 129 + wn * 64 + ni * 16 + l15];
        #pragma unroll
        for (int mi = 0; mi < 4; ++mi)
            #pragma unroll
            for (int ni = 0; ni < 4; ++ni)
                acc[mi][ni] = __builtin_amdgcn_mfma_f32_16x16x32_bf16(aF[mi], bF[ni], acc[mi][ni], 0, 0, 0);
    }
    // C/D: col = lane&15 (n), row = quad*4 + reg (m)
    const int m0 = mt * 128 + wm * 64 + quad * 4;
    const size_t n0 = (size_t)nt * 128 + wn * 64 + l15;
    #pragma unroll
    for (int mi = 0; mi < 4; ++mi)
        #pragma unroll
        for (int r = 0; r < 4; ++r) {
            unsigned short* Trow = T + (size_t)(m0 + mi * 16 + r) * BN + n0;
            #pragma unroll
            for (int ni = 0; ni < 4; ++ni)
                Trow[ni * 16] = f2bf(acc[mi][ni][r]);
        }
}

// ---- K2: LDS-staged 36-tap gather + maxpool3 + bias + BN stats -----------
// grid (o=128, b=64), 256 thr. LDS: 9 planes of 33 rows x 40 f32 (4-col pads
// both sides, row 32 = zeros). Unique taps: per plane 2 rows x 2 adjacent cols.
#define PLS (33 * 40)
__global__ __launch_bounds__(256) void k2_gather(const unsigned short* __restrict__ T,
                                                 const float* __restrict__ bias,
                                                 const int* __restrict__ hh,
                                                 const int* __restrict__ ww,
                                                 float* __restrict__ out,
                                                 float* __restrict__ stats) {
    __shared__ float lt[9 * PLS + 4];   // +4: harmless slack for the unused pair read at col 40
    const int tid = threadIdx.x;
    const int o = blockIdx.x, b = blockIdx.y;

    // zero pad columns (rows 0..31, cols {0..3, 36..39})
    #pragma unroll 3
    for (int i = tid; i < 9 * 32 * 8; i += 256) {
        int pr = i >> 3, c = i & 7;
        int kk = pr >> 5, r = pr & 31;
        lt[kk * PLS + r * 40 + (c < 4 ? c : c + 32)] = 0.f;
    }
    // zero row 32 of each plane (+ slack)
    for (int i = tid; i < 9 * 40 + 4; i += 256) {
        int kk = i / 40, c = i - kk * 40;
        lt[kk * PLS + 32 * 40 + c] = 0.f;
    }
    // stage 9 planes (1024 bf16 contiguous each) -> f32 padded rows
    const unsigned short* Tb = T + (size_t)o * BN + (size_t)b * 1024;
    for (int i = tid; i < 9 * 128; i += 256) {
        int kk = i >> 7, c8 = i & 127;
        us8 v = *reinterpret_cast<const us8*>(Tb + (size_t)kk * 128 * BN + c8 * 8);
        int r = c8 >> 2, cb = (c8 & 3) * 8;
        float* dst = &lt[kk * PLS + r * 40 + 4 + cb];
        f32x4 lo, hi;
        lo[0] = bf2f(v[0]); lo[1] = bf2f(v[1]); lo[2] = bf2f(v[2]); lo[3] = bf2f(v[3]);
        hi[0] = bf2f(v[4]); hi[1] = bf2f(v[5]); hi[2] = bf2f(v[6]); hi[3] = bf2f(v[7]);
        *reinterpret_cast<f32x4*>(dst) = lo;
        *reinterpret_cast<f32x4*>(dst + 4) = hi;
    }
    __syncthreads();

    int dh = 96 / hh[b]; if (dh < 1) dh = 1;
    int dw = 96 / ww[b]; if (dw < 1) dw = 1;
    const int q = tid & 31, prow = tid >> 5;

    // over y3 (or x3) = 0..2, floor((t+y3)/3) takes at most 2 values: base, base+1
    int gbase[3], fbase[3];
    int ridx[3][3], cidx[3][3];     // selector in {0,1}, block-uniform
    #pragma unroll
    for (int ki = 0; ki < 3; ++ki) {
        int t0 = (ki - 1) * dh;
        gbase[ki] = floordiv3(t0);
        #pragma unroll
        for (int y3 = 0; y3 < 3; ++y3) ridx[ki][y3] = floordiv3(y3 + t0) - gbase[ki];
    }
    #pragma unroll
    for (int kj = 0; kj < 3; ++kj) {
        int t0 = (kj - 1) * dw;
        fbase[kj] = floordiv3(t0);
        #pragma unroll
        for (int x3 = 0; x3 < 3; ++x3) cidx[kj][x3] = floordiv3(x3 + t0) - fbase[kj];
    }

    const float bias_o = bias[o];
    float s1 = 0.f, s2 = 0.f;
    #pragma unroll
    for (int it = 0; it < 4; ++it) {
        const int p = prow + it * 8;
        // 36 unique taps: v[ki][kj][rowvar][colvar]; col pairs fuse to ds_read2_b32
        float v[3][3][2][2];
        #pragma unroll
        for (int ki = 0; ki < 3; ++ki) {
            int r0 = p + gbase[ki];
            int rA = ((unsigned)r0 < 32u) ? r0 : 32;
            int r1 = r0 + 1;
            int rB = ((unsigned)r1 < 32u) ? r1 : 32;
            #pragma unroll
            for (int kj = 0; kj < 3; ++kj) {
                const float* bA = &lt[(ki * 3 + kj) * PLS + rA * 40 + q + 4 + fbase[kj]];
                const float* bB = &lt[(ki * 3 + kj) * PLS + rB * 40 + q + 4 + fbase[kj]];
                v[ki][kj][0][0] = bA[0]; v[ki][kj][0][1] = bA[1];
                v[ki][kj][1][0] = bB[0]; v[ki][kj][1][1] = bB[1];
            }
        }
        // u[ki][rowvar][x3] = sum_kj selected col
        float u[3][2][3];
        #pragma unroll
        for (int ki = 0; ki < 3; ++ki)
            #pragma unroll
            for (int a = 0; a < 2; ++a)
                #pragma unroll
                for (int x3 = 0; x3 < 3; ++x3)
                    u[ki][a][x3] = (cidx[0][x3] ? v[ki][0][a][1] : v[ki][0][a][0])
                                 + (cidx[1][x3] ? v[ki][1][a][1] : v[ki][1][a][0])
                                 + (cidx[2][x3] ? v[ki][2][a][1] : v[ki][2][a][0]);
        float best = -3.4e38f;
        #pragma unroll
        for (int y3 = 0; y3 < 3; ++y3)
            #pragma unroll
            for (int x3 = 0; x3 < 3; ++x3) {
                float s = (ridx[0][y3] ? u[0][1][x3] : u[0][0][x3])
                        + (ridx[1][y3] ? u[1][1][x3] : u[1][0][x3])
                        + (ridx[2][y3] ? u[2][1][x3] : u[2][0][x3]);
                best = fmaxf(best, s);
            }
        float val = best + bias_o;
        out[(((size_t)b * 128 + o) * 32 + p) * 32 + q] = val;
        s1 += val;
        s2 += val * val;
    }
    // full-wave reduction, one atomic pair per wave
    #pragma unroll
    for (int m = 32; m >= 1; m >>= 1) {
        s1 += __shfl_xor(s1, m, 64);
        s2 += __shfl_xor(s2, m, 64);
    }
    if ((tid & 63) == 0) {
        atomicAdd(&stats[o], s1);
        atomicAdd(&stats[128 + o], s2);
    }
}

// ---- K3: BN finalize + affine + relu, in-place on d_out ------------------
__global__ __launch_bounds__(256) void k3_bn(float4* __restrict__ out,
                                             const float* __restrict__ stats,
                                             const float* __restrict__ gamma,
                                             const float* __restrict__ beta) {
    int i4 = blockIdx.x * 256 + threadIdx.x;   // 0..2097151
    int o = (i4 >> 8) & 127;
    const float invN = 1.0f / 65536.0f;
    float mean = stats[o] * invN;
    float var = stats[128 + o] * invN - mean * mean;
    float inv = rsqrtf(var + 1e-5f);
    float sc = gamma[o] * inv;
    float sh = beta[o] - mean * sc;
    float4 v = out[i4];
    v.x = fmaxf(fmaf(v.x, sc, sh), 0.f);
    v.y = fmaxf(fmaf(v.y, sc, sh), 0.f);
    v.z = fmaxf(fmaf(v.z, sc, sh), 0.f);
    v.w = fmaxf(fmaf(v.w, sc, sh), 0.f);
    out[i4] = v;
}

extern "C" void kernel_launch(void* const* d_in, const int* in_sizes, int n_in,
                              void* d_out, int out_size, void* d_ws, size_t ws_size,
                              hipStream_t stream) {
    const float* x     = (const float*)d_in[0];
    const int*   h     = (const int*)d_in[1];
    const int*   w     = (const int*)d_in[2];
    const float* wt    = (const float*)d_in[3];
    const float* bias  = (const float*)d_in[4];
    const float* gamma = (const float*)d_in[5];
    const float* beta  = (const float*)d_in[6];
    float* out = (float*)d_out;
    char* ws = (char*)d_ws;

    float*          stats = (float*)(ws + 0);
    unsigned short* A     = (unsigned short*)(ws + 4096);
    unsigned short* XbT   = (unsigned short*)(ws + 151552);
    unsigned short* T     = (unsigned short*)(ws + 8540160);

    hipMemsetAsync(stats, 0, 1024, stream);
    k0_x<<<dim3(16, 64), 256, 0, stream>>>(x, XbT);
    k0_w<<<288, 256, 0, stream>>>(wt, A);
    k1_gemm<<<dim3(512, 9), 256, 0, stream>>>(XbT, A, T);
    k2_gather<<<dim3(128, 64), 256, 0, stream>>>(T, bias, h, w, out, stats);
    k3_bn<<<8192, 256, 0, stream>>>((float4*)out, stats, gamma, beta);
}

// Round 5
// 185.735 us; speedup vs baseline: 3.5681x; 1.2658x over previous
//
#include <hip/hip_runtime.h>
#include <hip/hip_bf16.h>

// SizeInvBlock: upsample3x(nearest) -> per-sample dilated 3x3 conv -> maxpool3 -> BN(train) -> relu
// Factorization: conv on upsampled image only samples original 32x32 pixels:
//   out[o,y,x] = bias[o] + sum_{ki,kj} T[kikj][o, r_ki(y), c_kj(x)]
//   T[kikj][o,i,j] = sum_c W[o,c,ki,kj] * X[c,i,j]   (one GEMM, 9x fewer FLOPs than direct conv)
// R5: (1) k1 epilogue: acc -> bf16 -> LDS tile (stride 132, conflict-free) ->
//         coalesced global_store_dwordx4 (R4 used 64 scattered 2B stores/thread)
//     (2) k2: 1024 thr/block, 1 output/thread -> 2 blocks/CU = ~32 waves/CU
//         (R4: 12 waves/CU, latency-stalled at 27.7% occupancy); block-level
//         LDS stats reduction -> 2 atomics/block.
//
// ws layout (bytes):
//   [0,      1024)    stats: sum[128], sumsq[128] (f32, atomic)
//   [4096,   151552)  A bf16 [1152][64]   (m = (ki*3+kj)*128 + o, k = cin)
//   [151552, 8540160) XbT bf16 [64 b][1024 n][64 c]
//   [8540160,159535104) T bf16 [1152][65536]  (n = b*1024 + i*32 + j)

typedef __attribute__((ext_vector_type(8))) short bf16x8;
typedef __attribute__((ext_vector_type(4))) float f32x4;
typedef __attribute__((ext_vector_type(8))) unsigned short us8;

#define BN 65536   // T n-dimension (all 64 samples)

__device__ __forceinline__ unsigned short f2bf(float f) {
    unsigned u = __float_as_uint(f);
    u += 0x7fffu + ((u >> 16) & 1u);
    return (unsigned short)(u >> 16);
}
__device__ __forceinline__ float bf2f(unsigned short s) {
    return __uint_as_float(((unsigned)s) << 16);
}
__device__ __forceinline__ int floordiv3(int t) {
    return (t >= 0) ? (t / 3) : -((2 - t) / 3);
}

// ---- K0a: X fp32 [b][c][1024] -> XbT bf16 [b][n][c] ----------------------
__global__ __launch_bounds__(256) void k0_x(const float* __restrict__ x,
                                            unsigned short* __restrict__ xbt) {
    const int tid = threadIdx.x;
    const int n = blockIdx.x * 64 + (tid & 63);
    const int cg = tid >> 6;
    const int b = blockIdx.y;
    #pragma unroll
    for (int j2 = 0; j2 < 2; ++j2) {
        int c8 = cg * 2 + j2;                     // 0..7
        us8 r;
        #pragma unroll
        for (int j = 0; j < 8; ++j)
            r[j] = f2bf(x[(((b << 6) + c8 * 8 + j) << 10) + n]);
        *reinterpret_cast<us8*>(xbt + ((size_t)(b << 10) + n) * 64 + c8 * 8) = r;
    }
}

// ---- K0b: W fp32 [o][c][ki][kj] -> A bf16 [(kikj)*128+o][c] --------------
__global__ __launch_bounds__(256) void k0_w(const float* __restrict__ w, unsigned short* __restrict__ A) {
    int gid = blockIdx.x * 256 + threadIdx.x;  // < 73728
    int m = gid >> 6, c = gid & 63;
    int kk = m >> 7, o = m & 127;
    A[gid] = f2bf(w[(o * 64 + c) * 9 + kk]);
}

// ---- K1: GEMM A[1152x64] @ XbT^T[64 x 65536] -> T bf16 -------------------
// grid (512 nt, 9 mt), 256 thr (2x2 wave grid), tile 128m x 128n, K=64.
// Input LDS: 16B units, unit = kg*129 + row. Output LDS: bf16 [128m][132 stride].
__global__ __launch_bounds__(256) void k1_gemm(const unsigned short* __restrict__ XbT,
                                               const unsigned short* __restrict__ A,
                                               unsigned short* __restrict__ T) {
    __shared__ union {
        struct { us8 lA[8 * 129]; us8 lB[8 * 129]; } in;   // 33024 B
        unsigned short ot[128 * 132];                       // 33792 B
    } sm;
    const int tid = threadIdx.x;
    const int nt = blockIdx.x;    // 0..511
    const int mt = blockIdx.y;    // 0..8

    #pragma unroll
    for (int i = 0; i < 4; ++i) {
        int gid = i * 256 + tid;
        int row = gid >> 3, ch = gid & 7; // ch fastest -> coalesced 16B/lane
        sm.in.lA[ch * 129 + row] = *reinterpret_cast<const us8*>(
            A + (size_t)(mt * 128 + row) * 64 + ch * 8);
    }
    #pragma unroll
    for (int i = 0; i < 4; ++i) {
        int gid = i * 256 + tid;
        int row = gid >> 3, ch = gid & 7;
        sm.in.lB[ch * 129 + row] = *reinterpret_cast<const us8*>(
            XbT + ((size_t)nt * 128 + row) * 64 + ch * 8);
    }
    __syncthreads();

    const int wave = tid >> 6, lane = tid & 63;
    const int quad = lane >> 4, l15 = lane & 15;
    const int wm = wave & 1, wn = wave >> 1;
    const bf16x8* pA = reinterpret_cast<const bf16x8*>(sm.in.lA);
    const bf16x8* pB = reinterpret_cast<const bf16x8*>(sm.in.lB);

    f32x4 acc[4][4] = {};
    #pragma unroll
    for (int ks = 0; ks < 2; ++ks) {
        const int kg = ks * 4 + quad;
        bf16x8 aF[4], bF[4];
        #pragma unroll
        for (int mi = 0; mi < 4; ++mi)
            aF[mi] = pA[kg * 129 + wm * 64 + mi * 16 + l15];
        #pragma unroll
        for (int ni = 0; ni < 4; ++ni)
            bF[ni] = pB[kg * 129 + wn * 64 + ni * 16 + l15];
        #pragma unroll
        for (int mi = 0; mi < 4; ++mi)
            #pragma unroll
            for (int ni = 0; ni < 4; ++ni)
                acc[mi][ni] = __builtin_amdgcn_mfma_f32_16x16x32_bf16(aF[mi], bF[ni], acc[mi][ni], 0, 0, 0);
    }
    __syncthreads();   // frags consumed; safe to overwrite with output tile

    // C/D: col = lane&15 (n), row = quad*4 + reg (m). Write bf16 to LDS tile.
    {
        const int mloc = wm * 64 + quad * 4;          // local m base
        const int nloc = wn * 64 + l15;               // local n base
        #pragma unroll
        for (int mi = 0; mi < 4; ++mi)
            #pragma unroll
            for (int r = 0; r < 4; ++r) {
                unsigned short* dst = &sm.ot[(mloc + mi * 16 + r) * 132 + nloc];
                #pragma unroll
                for (int ni = 0; ni < 4; ++ni)
                    dst[ni * 16] = f2bf(acc[mi][ni][r]);
            }
    }
    __syncthreads();

    // coalesced store: 2048 us8 chunks; lane-consecutive chunks along n
    #pragma unroll
    for (int i = 0; i < 8; ++i) {
        int cid = i * 256 + tid;
        int row = cid >> 4, ch = cid & 15;
        us8 v = *reinterpret_cast<const us8*>(&sm.ot[row * 132 + ch * 8]);
        *reinterpret_cast<us8*>(T + (size_t)(mt * 128 + row) * BN + (size_t)nt * 128 + ch * 8) = v;
    }
}

// ---- K2: LDS-staged 36-tap gather + maxpool3 + bias + BN stats -----------
// grid (o=128, b=64), 1024 thr (1 output each): 2 blocks/CU -> ~32 waves/CU.
// LDS: 9 planes of 33 rows x 40 f32 (4-col pads both sides, row 32 = zeros).
#define PLS (33 * 40)
__global__ __launch_bounds__(1024) void k2_gather(const unsigned short* __restrict__ T,
                                                  const float* __restrict__ bias,
                                                  const int* __restrict__ hh,
                                                  const int* __restrict__ ww,
                                                  float* __restrict__ out,
                                                  float* __restrict__ stats) {
    __shared__ float lt[9 * PLS + 4];
    __shared__ float red[32];
    const int tid = threadIdx.x;
    const int o = blockIdx.x, b = blockIdx.y;

    // zero pad columns (rows 0..31, cols {0..3, 36..39})
    #pragma unroll 3
    for (int i = tid; i < 9 * 32 * 8; i += 1024) {
        int pr = i >> 3, c = i & 7;
        int kk = pr >> 5, r = pr & 31;
        lt[kk * PLS + r * 40 + (c < 4 ? c : c + 32)] = 0.f;
    }
    // zero row 32 of each plane (+ slack)
    for (int i = tid; i < 9 * 40 + 4; i += 1024) {
        int kk = i / 40, c = i - kk * 40;
        lt[kk * PLS + 32 * 40 + c] = 0.f;
    }
    // stage 9 planes (1024 bf16 contiguous each) -> f32 padded rows
    const unsigned short* Tb = T + (size_t)o * BN + (size_t)b * 1024;
    for (int i = tid; i < 9 * 128; i += 1024) {
        int kk = i >> 7, c8 = i & 127;
        us8 v = *reinterpret_cast<const us8*>(Tb + (size_t)kk * 128 * BN + c8 * 8);
        int r = c8 >> 2, cb = (c8 & 3) * 8;
        float* dst = &lt[kk * PLS + r * 40 + 4 + cb];
        f32x4 lo, hi;
        lo[0] = bf2f(v[0]); lo[1] = bf2f(v[1]); lo[2] = bf2f(v[2]); lo[3] = bf2f(v[3]);
        hi[0] = bf2f(v[4]); hi[1] = bf2f(v[5]); hi[2] = bf2f(v[6]); hi[3] = bf2f(v[7]);
        *reinterpret_cast<f32x4*>(dst) = lo;
        *reinterpret_cast<f32x4*>(dst + 4) = hi;
    }
    __syncthreads();

    int dh = 96 / hh[b]; if (dh < 1) dh = 1;
    int dw = 96 / ww[b]; if (dw < 1) dw = 1;
    const int q = tid & 31, p = tid >> 5;

    // over y3 (or x3) = 0..2, floor((t+y3)/3) takes at most 2 values: base, base+1
    int gbase[3], fbase[3];
    int ridx[3][3], cidx[3][3];     // selector in {0,1}, block-uniform
    #pragma unroll
    for (int ki = 0; ki < 3; ++ki) {
        int t0 = (ki - 1) * dh;
        gbase[ki] = floordiv3(t0);
        #pragma unroll
        for (int y3 = 0; y3 < 3; ++y3) ridx[ki][y3] = floordiv3(y3 + t0) - gbase[ki];
    }
    #pragma unroll
    for (int kj = 0; kj < 3; ++kj) {
        int t0 = (kj - 1) * dw;
        fbase[kj] = floordiv3(t0);
        #pragma unroll
        for (int x3 = 0; x3 < 3; ++x3) cidx[kj][x3] = floordiv3(x3 + t0) - fbase[kj];
    }

    // 36 unique taps, consumed per-ki to keep live range small:
    // u[ki][rowvar][x3] = sum_kj selected col
    float u[3][2][3];
    #pragma unroll
    for (int ki = 0; ki < 3; ++ki) {
        int r0 = p + gbase[ki];
        int rA = ((unsigned)r0 < 32u) ? r0 : 32;
        int r1 = r0 + 1;
        int rB = ((unsigned)r1 < 32u) ? r1 : 32;
        float v[3][2][2];
        #pragma unroll
        for (int kj = 0; kj < 3; ++kj) {
            const float* bA = &lt[(ki * 3 + kj) * PLS + rA * 40 + q + 4 + fbase[kj]];
            const float* bB = &lt[(ki * 3 + kj) * PLS + rB * 40 + q + 4 + fbase[kj]];
            v[kj][0][0] = bA[0]; v[kj][0][1] = bA[1];
            v[kj][1][0] = bB[0]; v[kj][1][1] = bB[1];
        }
        #pragma unroll
        for (int a = 0; a < 2; ++a)
            #pragma unroll
            for (int x3 = 0; x3 < 3; ++x3)
                u[ki][a][x3] = (cidx[0][x3] ? v[0][a][1] : v[0][a][0])
                             + (cidx[1][x3] ? v[1][a][1] : v[1][a][0])
                             + (cidx[2][x3] ? v[2][a][1] : v[2][a][0]);
    }
    float best = -3.4e38f;
    #pragma unroll
    for (int y3 = 0; y3 < 3; ++y3)
        #pragma unroll
        for (int x3 = 0; x3 < 3; ++x3) {
            float s = (ridx[0][y3] ? u[0][1][x3] : u[0][0][x3])
                    + (ridx[1][y3] ? u[1][1][x3] : u[1][0][x3])
                    + (ridx[2][y3] ? u[2][1][x3] : u[2][0][x3]);
            best = fmaxf(best, s);
        }
    float val = best + bias[o];
    out[(((size_t)b * 128 + o) * 32 + p) * 32 + q] = val;

    // stats: wave reduce -> LDS -> block reduce -> 2 atomics
    float s1 = val, s2 = val * val;
    #pragma unroll
    for (int m = 32; m >= 1; m >>= 1) {
        s1 += __shfl_xor(s1, m, 64);
        s2 += __shfl_xor(s2, m, 64);
    }
    if ((tid & 63) == 0) {
        red[tid >> 6] = s1;
        red[16 + (tid >> 6)] = s2;
    }
    __syncthreads();
    if (tid < 64) {
        float a1 = (tid < 16) ? red[tid] : 0.f;
        float a2 = (tid < 16) ? red[16 + tid] : 0.f;
        #pragma unroll
        for (int m = 8; m >= 1; m >>= 1) {
            a1 += __shfl_xor(a1, m, 64);
            a2 += __shfl_xor(a2, m, 64);
        }
        if (tid == 0) {
            atomicAdd(&stats[o], a1);
            atomicAdd(&stats[128 + o], a2);
        }
    }
}

// ---- K3: BN finalize + affine + relu, in-place on d_out ------------------
__global__ __launch_bounds__(256) void k3_bn(float4* __restrict__ out,
                                             const float* __restrict__ stats,
                                             const float* __restrict__ gamma,
                                             const float* __restrict__ beta) {
    int i4 = blockIdx.x * 256 + threadIdx.x;   // 0..2097151
    int o = (i4 >> 8) & 127;
    const float invN = 1.0f / 65536.0f;
    float mean = stats[o] * invN;
    float var = stats[128 + o] * invN - mean * mean;
    float inv = rsqrtf(var + 1e-5f);
    float sc = gamma[o] * inv;
    float sh = beta[o] - mean * sc;
    float4 v = out[i4];
    v.x = fmaxf(fmaf(v.x, sc, sh), 0.f);
    v.y = fmaxf(fmaf(v.y, sc, sh), 0.f);
    v.z = fmaxf(fmaf(v.z, sc, sh), 0.f);
    v.w = fmaxf(fmaf(v.w, sc, sh), 0.f);
    out[i4] = v;
}

extern "C" void kernel_launch(void* const* d_in, const int* in_sizes, int n_in,
                              void* d_out, int out_size, void* d_ws, size_t ws_size,
                              hipStream_t stream) {
    const float* x     = (const float*)d_in[0];
    const int*   h     = (const int*)d_in[1];
    const int*   w     = (const int*)d_in[2];
    const float* wt    = (const float*)d_in[3];
    const float* bias  = (const float*)d_in[4];
    const float* gamma = (const float*)d_in[5];
    const float* beta  = (const float*)d_in[6];
    float* out = (float*)d_out;
    char* ws = (char*)d_ws;

    float*          stats = (float*)(ws + 0);
    unsigned short* A     = (unsigned short*)(ws + 4096);
    unsigned short* XbT   = (unsigned short*)(ws + 151552);
    unsigned short* T     = (unsigned short*)(ws + 8540160);

    hipMemsetAsync(stats, 0, 1024, stream);
    k0_x<<<dim3(16, 64), 256, 0, stream>>>(x, XbT);
    k0_w<<<288, 256, 0, stream>>>(wt, A);
    k1_gemm<<<dim3(512, 9), 256, 0, stream>>>(XbT, A, T);
    k2_gather<<<dim3(128, 64), 1024, 0, stream>>>(T, bias, h, w, out, stats);
    k3_bn<<<8192, 256, 0, stream>>>((float4*)out, stats, gamma, beta);
}